// Round 1
// baseline (599.226 us; speedup 1.0000x reference)
//
#include <hip/hip_runtime.h>
#include <hip/hip_bf16.h>

// GAT layer, N=8192, F_in=512, F_out=128.
// Key identity: exp(leaky_relu(s1[i]+s2[j])) = pos ? exp(s1)exp(s2) : exp(.2 s1)exp(.2 s2)
// => per-pair work is compare+select+mul; no per-pair exp, no NxN materialization.
// Pipeline: k0 transpose W->WT(bf16); k1 h=X@W (MFMA), emits hT(bf16), per-row
// (E1,E1s,T1=exp(-s1)) and per-col packed bf16 (E2,E2s); k2 one-pass masked
// softmax-weighted accumulation P@h with 4-way column split (fp32 partials);
// k3 combine + normalize + elu.

typedef __attribute__((ext_vector_type(4))) float f32x4;
typedef __attribute__((ext_vector_type(8))) short s16x8;

#define N_NODES 8192
#define F_IN 512
#define F_OUT 128
#define JS 4
#define JCHUNK (N_NODES / JS)

static __device__ __forceinline__ short f2bf(float f) {
  __hip_bfloat16 h = __float2bfloat16(f);
  return __builtin_bit_cast(short, h);
}

// ---------------- k0: W (512x128 f32) -> WT (128x512 bf16) ----------------
__global__ void k0_wt(const float* __restrict__ W, unsigned short* __restrict__ WT) {
  int idx = blockIdx.x * 256 + threadIdx.x;   // 65536 elements
  int k = idx >> 7, f = idx & 127;
  WT[(size_t)f * F_IN + k] = (unsigned short)f2bf(W[idx]);
}

// ---------------- k1: h = X@W, emit hT(bf16), rowdat, packedE ----------------
__global__ __launch_bounds__(256) void k1_h(const float* __restrict__ X,
    const unsigned short* __restrict__ WT, const float* __restrict__ a,
    unsigned short* __restrict__ hT, f32x4* __restrict__ rowdat,
    unsigned* __restrict__ pE) {
  int wave = threadIdx.x >> 6, lane = threadIdx.x & 63;
  int lrow = lane & 15, grp = lane >> 4;
  int waveRow = blockIdx.x * 64 + wave * 16;

  const float* Arow = X + (size_t)(waveRow + lrow) * F_IN + grp * 8;
  f32x4 acc[8];
#pragma unroll
  for (int n = 0; n < 8; n++) acc[n] = (f32x4)(0.0f);

  for (int k0 = 0; k0 < F_IN; k0 += 32) {
    f32x4 x0 = *(const f32x4*)(Arow + k0);
    f32x4 x1 = *(const f32x4*)(Arow + k0 + 4);
    s16x8 af;
    af[0] = f2bf(x0[0]); af[1] = f2bf(x0[1]); af[2] = f2bf(x0[2]); af[3] = f2bf(x0[3]);
    af[4] = f2bf(x1[0]); af[5] = f2bf(x1[1]); af[6] = f2bf(x1[2]); af[7] = f2bf(x1[3]);
#pragma unroll
    for (int n = 0; n < 8; n++) {
      s16x8 bf = *(const s16x8*)(WT + (size_t)(n * 16 + lrow) * F_IN + k0 + grp * 8);
      acc[n] = __builtin_amdgcn_mfma_f32_16x16x32_bf16(af, bf, acc[n], 0, 0, 0);
    }
  }

  // epilogue: write hT, compute s1/s2 per row, then per-row/per-col exp tables
  float a1v[8], a2v[8];
#pragma unroll
  for (int n = 0; n < 8; n++) {
    a1v[n] = a[n * 16 + lrow];
    a2v[n] = a[128 + n * 16 + lrow];
  }
  float s1p[4] = {0.f, 0.f, 0.f, 0.f}, s2p[4] = {0.f, 0.f, 0.f, 0.f};
#pragma unroll
  for (int n = 0; n < 8; n++) {
#pragma unroll
    for (int r = 0; r < 4; r++) {
      float v = acc[n][r];               // C/D layout: col=lane&15, row=grp*4+r
      s1p[r] += v * a1v[n];
      s2p[r] += v * a2v[n];
      hT[(size_t)(n * 16 + lrow) * N_NODES + waveRow + grp * 4 + r] =
          (unsigned short)f2bf(v);
    }
  }
#pragma unroll
  for (int r = 0; r < 4; r++) {
#pragma unroll
    for (int m = 1; m < 16; m <<= 1) {
      s1p[r] += __shfl_xor(s1p[r], m, 64);
      s2p[r] += __shfl_xor(s2p[r], m, 64);
    }
  }
  if (lrow == 0) {
#pragma unroll
    for (int r = 0; r < 4; r++) {
      int i = waveRow + grp * 4 + r;
      float s1 = s1p[r], s2 = s2p[r];
      f32x4 rd;
      rd[0] = expf(s1);          // E1
      rd[1] = expf(0.2f * s1);   // E1s
      rd[2] = expf(-s1);         // T1: pos <=> E2 > T1
      rd[3] = 0.f;
      rowdat[i] = rd;
      unsigned e2  = (unsigned)(unsigned short)f2bf(expf(s2));
      unsigned e2s = (unsigned)(unsigned short)f2bf(expf(0.2f * s2));
      pE[i] = (e2s << 16) | e2;
    }
  }
}

// ---------------- k2: one-pass masked P@h + row sums (4-way j split) --------
__global__ __launch_bounds__(256) void k2_main(const int* __restrict__ adj,
    const unsigned short* __restrict__ hT, const f32x4* __restrict__ rowdat,
    const unsigned* __restrict__ pE, float* __restrict__ accws,
    float* __restrict__ denws) {
  int js = blockIdx.x & (JS - 1);
  int rb = blockIdx.x >> 2;
  int wave = threadIdx.x >> 6, lane = threadIdx.x & 63;
  int lrow = lane & 15, grp = lane >> 4;
  int waveRow = rb * 64 + wave * 16;
  int i0 = waveRow + lrow;

  f32x4 rd = rowdat[i0];
  float E1 = rd[0], E1s = rd[1], T1 = rd[2];
  const int* adjRow = adj + (size_t)i0 * N_NODES;
  int jlo = js * JCHUNK;

  f32x4 acc[8];
#pragma unroll
  for (int n = 0; n < 8; n++) acc[n] = (f32x4)(0.0f);
  float dsum = 0.f;

#define PROC(adjv, pe, e)                                            \
  {                                                                  \
    unsigned pu = (pe);                                              \
    float E2  = __builtin_bit_cast(float, pu << 16);                 \
    float E2s = __builtin_bit_cast(float, pu & 0xffff0000u);         \
    float p = (E2 > T1) ? E1 * E2 : E1s * E2s;                       \
    p = ((adjv) != 0) ? p : 0.f;                                     \
    dsum += p;                                                       \
    af[e] = f2bf(p);                                                 \
  }

  for (int j0 = jlo; j0 < jlo + JCHUNK; j0 += 32) {
    int jj = j0 + grp * 8;
    const int4* ap = (const int4*)(adjRow + jj);
    int4 A0 = ap[0];
    int4 A1 = ap[1];
    const uint4* pp = (const uint4*)(pE + jj);
    uint4 P0 = pp[0];
    uint4 P1 = pp[1];
    s16x8 af;
    PROC(A0.x, P0.x, 0); PROC(A0.y, P0.y, 1);
    PROC(A0.z, P0.z, 2); PROC(A0.w, P0.w, 3);
    PROC(A1.x, P1.x, 4); PROC(A1.y, P1.y, 5);
    PROC(A1.z, P1.z, 6); PROC(A1.w, P1.w, 7);
    const unsigned short* hTj = hT + jj;
#pragma unroll
    for (int n = 0; n < 8; n++) {
      s16x8 bf = *(const s16x8*)(hTj + (size_t)(n * 16 + lrow) * N_NODES);
      acc[n] = __builtin_amdgcn_mfma_f32_16x16x32_bf16(af, bf, acc[n], 0, 0, 0);
    }
  }
#undef PROC

  // row denominator: sum the 4 k-groups (lanes l, l^16, l^32, l^48 share lrow)
  dsum += __shfl_xor(dsum, 16, 64);
  dsum += __shfl_xor(dsum, 32, 64);
  if (lane < 16) denws[js * N_NODES + waveRow + lane] = dsum;

#pragma unroll
  for (int n = 0; n < 8; n++) {
#pragma unroll
    for (int r = 0; r < 4; r++) {
      accws[((size_t)js * N_NODES + waveRow + grp * 4 + r) * F_OUT + n * 16 + lrow] =
          acc[n][r];
    }
  }
}

// ---------------- k3: combine partials, normalize, elu ----------------
__global__ void k3_fin(const float* __restrict__ accws,
                       const float* __restrict__ denws, float* __restrict__ out) {
  int idx = blockIdx.x * 256 + threadIdx.x;   // 1048576 elements
  int i = idx >> 7;
  const int S = N_NODES * F_OUT;
  float s = accws[idx] + accws[idx + S] + accws[idx + 2 * S] + accws[idx + 3 * S];
  float d = denws[i] + denws[i + N_NODES] + denws[i + 2 * N_NODES] +
            denws[i + 3 * N_NODES];
  float v = s / d;
  out[idx] = v > 0.f ? v : expm1f(v);
}

extern "C" void kernel_launch(void* const* d_in, const int* in_sizes, int n_in,
                              void* d_out, int out_size, void* d_ws, size_t ws_size,
                              hipStream_t stream) {
  const float* X   = (const float*)d_in[0];
  const int*   adj = (const int*)d_in[1];
  const float* W   = (const float*)d_in[2];
  const float* a   = (const float*)d_in[3];
  float* out = (float*)d_out;

  char* ws = (char*)d_ws;
  size_t off = 0;
  unsigned short* WT = (unsigned short*)(ws + off); off += (size_t)F_OUT * F_IN * 2;
  unsigned short* hT = (unsigned short*)(ws + off); off += (size_t)F_OUT * N_NODES * 2;
  f32x4* rowdat = (f32x4*)(ws + off); off += (size_t)N_NODES * 16;
  unsigned* pE = (unsigned*)(ws + off); off += (size_t)N_NODES * 4;
  float* accws = (float*)(ws + off); off += (size_t)JS * N_NODES * F_OUT * 4;
  float* denws = (float*)(ws + off); off += (size_t)JS * N_NODES * 4;
  (void)ws_size; (void)in_sizes; (void)n_in; (void)out_size;

  k0_wt<<<(F_IN * F_OUT) / 256, 256, 0, stream>>>(W, WT);
  k1_h<<<N_NODES / 64, 256, 0, stream>>>(X, WT, a, hT, rowdat, pE);
  k2_main<<<(N_NODES / 64) * JS, 256, 0, stream>>>(adj, hT, rowdat, pE, accws, denws);
  k3_fin<<<(N_NODES * F_OUT) / 256, 256, 0, stream>>>(accws, denws, out);
}

// Round 2
// 542.808 us; speedup vs baseline: 1.1039x; 1.1039x over previous
//
#include <hip/hip_runtime.h>
#include <hip/hip_bf16.h>

// GAT layer, N=8192, F_in=512, F_out=128.
// exp(leaky_relu(s1+s2)) = pos ? exp(s1)exp(s2) : exp(.2 s1)exp(.2 s2)
// => per-pair work is compare+select+mul; no NxN materialization.
// r2 changes: k2 occupancy (JS=16 -> 2048 blocks, 32 waves/CU);
// k1 split into wa-precompute + streaming X pass + swapped-operand GEMM
// writing hT directly (was: 128-block kernel with 2B-scatter stores).

typedef __attribute__((ext_vector_type(4))) float f32x4;
typedef __attribute__((ext_vector_type(8))) short s16x8;

#define N_NODES 8192
#define F_IN 512
#define F_OUT 128

static __device__ __forceinline__ short f2bf(float f) {
  __hip_bfloat16 h = __float2bfloat16(f);
  return __builtin_bit_cast(short, h);
}

// ---------------- k0a: W (512x128 f32) -> WT (128x512 bf16) ----------------
__global__ void k0a_wt(const float* __restrict__ W, unsigned short* __restrict__ WT) {
  int idx = blockIdx.x * 256 + threadIdx.x;   // 65536 elements
  int k = idx >> 7, f = idx & 127;
  WT[(size_t)f * F_IN + k] = (unsigned short)f2bf(W[idx]);
}

// ---------------- k0c: wa1[k] = sum_f W[k][f] a1[f]; wa2 likewise ----------
__global__ void k0c_wa(const float* __restrict__ W, const float* __restrict__ a,
                       float* __restrict__ wa) {
  int k = blockIdx.x * 256 + threadIdx.x;
  if (k >= F_IN) return;
  const float* Wr = W + (size_t)k * F_OUT;
  float d1 = 0.f, d2 = 0.f;
#pragma unroll 8
  for (int f = 0; f < F_OUT; f += 4) {
    f32x4 w  = *(const f32x4*)(Wr + f);
    f32x4 a1 = *(const f32x4*)(a + f);
    f32x4 a2 = *(const f32x4*)(a + F_OUT + f);
    d1 += w[0] * a1[0] + w[1] * a1[1] + w[2] * a1[2] + w[3] * a1[3];
    d2 += w[0] * a2[0] + w[1] * a2[1] + w[2] * a2[2] + w[3] * a2[3];
  }
  wa[k] = d1;
  wa[F_IN + k] = d2;
}

// ------- k0b: Xb = bf16(X); s1,s2 = X@wa per row; rowdat + pE tables -------
__global__ __launch_bounds__(256) void k0b_x(const float* __restrict__ X,
    const float* __restrict__ wa, unsigned short* __restrict__ Xb,
    f32x4* __restrict__ rowdat, unsigned* __restrict__ pE) {
  int wave = threadIdx.x >> 6, lane = threadIdx.x & 63;
  int i = blockIdx.x * 4 + wave;            // one wave per row
  const float* Xr = X + (size_t)i * F_IN + lane * 8;
  f32x4 x0 = ((const f32x4*)Xr)[0];
  f32x4 x1 = ((const f32x4*)Xr)[1];
  f32x4 w10 = ((const f32x4*)(wa + lane * 8))[0];
  f32x4 w11 = ((const f32x4*)(wa + lane * 8))[1];
  f32x4 w20 = ((const f32x4*)(wa + F_IN + lane * 8))[0];
  f32x4 w21 = ((const f32x4*)(wa + F_IN + lane * 8))[1];

  s16x8 xb;
#pragma unroll
  for (int e = 0; e < 4; e++) { xb[e] = f2bf(x0[e]); xb[e + 4] = f2bf(x1[e]); }
  *(s16x8*)(Xb + (size_t)i * F_IN + lane * 8) = xb;

  float d1 = 0.f, d2 = 0.f;
#pragma unroll
  for (int e = 0; e < 4; e++) {
    d1 += x0[e] * w10[e] + x1[e] * w11[e];
    d2 += x0[e] * w20[e] + x1[e] * w21[e];
  }
#pragma unroll
  for (int m = 1; m < 64; m <<= 1) {
    d1 += __shfl_xor(d1, m, 64);
    d2 += __shfl_xor(d2, m, 64);
  }
  if (lane == 0) {
    float s1 = d1, s2 = d2;
    f32x4 rd;
    rd[0] = expf(s1);          // E1
    rd[1] = expf(0.2f * s1);   // E1s
    rd[2] = expf(-s1);         // T1: pos <=> E2 > T1
    rd[3] = 0.f;
    rowdat[i] = rd;
    unsigned e2  = (unsigned)(unsigned short)f2bf(expf(s2));
    unsigned e2s = (unsigned)(unsigned short)f2bf(expf(0.2f * s2));
    pE[i] = (e2s << 16) | e2;
  }
}

// ------- k1: hT[f][node] = sum_k WT[f][k] Xb[node][k]  (swapped-operand) ----
__global__ __launch_bounds__(256) void k1_gemm(const unsigned short* __restrict__ WT,
    const unsigned short* __restrict__ Xb, unsigned short* __restrict__ hT) {
  int wave = threadIdx.x >> 6, lane = threadIdx.x & 63;
  int lrow = lane & 15, grp = lane >> 4;
  int g = blockIdx.x >> 1;                       // 64-node group
  int ftile = (blockIdx.x & 1) * 4 + wave;       // 0..7

  const unsigned short* Ar = WT + (size_t)(ftile * 16 + lrow) * F_IN + grp * 8;
  const unsigned short* Br = Xb + (size_t)(g * 64 + lrow) * F_IN + grp * 8;

  f32x4 acc[4];
#pragma unroll
  for (int nt = 0; nt < 4; nt++) acc[nt] = (f32x4)(0.0f);

  for (int k0 = 0; k0 < F_IN; k0 += 32) {
    s16x8 af = *(const s16x8*)(Ar + k0);
#pragma unroll
    for (int nt = 0; nt < 4; nt++) {
      s16x8 bf = *(const s16x8*)(Br + (size_t)nt * 16 * F_IN + k0);
      acc[nt] = __builtin_amdgcn_mfma_f32_16x16x32_bf16(af, bf, acc[nt], 0, 0, 0);
    }
  }
  // C[row = f-offset grp*4+r][col = node-offset lrow]
#pragma unroll
  for (int nt = 0; nt < 4; nt++)
#pragma unroll
    for (int r = 0; r < 4; r++)
      hT[(size_t)(ftile * 16 + grp * 4 + r) * N_NODES + g * 64 + nt * 16 + lrow] =
          (unsigned short)f2bf(acc[nt][r]);
}

// ---------------- k2: one-pass masked P@h + row sums (JS-way j split) -------
template <int JS>
__global__ __launch_bounds__(256) void k2_main(const int* __restrict__ adj,
    const unsigned short* __restrict__ hT, const f32x4* __restrict__ rowdat,
    const unsigned* __restrict__ pE, float* __restrict__ accws,
    float* __restrict__ denws) {
  constexpr int JCHUNK = N_NODES / JS;
  int js = blockIdx.x & (JS - 1);
  int rb = blockIdx.x / JS;
  int wave = threadIdx.x >> 6, lane = threadIdx.x & 63;
  int lrow = lane & 15, grp = lane >> 4;
  int waveRow = rb * 64 + wave * 16;
  int i0 = waveRow + lrow;

  f32x4 rd = rowdat[i0];
  float E1 = rd[0], E1s = rd[1], T1 = rd[2];
  const int* adjRow = adj + (size_t)i0 * N_NODES;
  int jlo = js * JCHUNK;

  f32x4 acc[8];
#pragma unroll
  for (int n = 0; n < 8; n++) acc[n] = (f32x4)(0.0f);
  float dsum = 0.f;

#define PROC(adjv, pe, e)                                            \
  {                                                                  \
    unsigned pu = (pe);                                              \
    float E2  = __builtin_bit_cast(float, pu << 16);                 \
    float E2s = __builtin_bit_cast(float, pu & 0xffff0000u);         \
    float p = (E2 > T1) ? E1 * E2 : E1s * E2s;                       \
    p = ((adjv) != 0) ? p : 0.f;                                     \
    dsum += p;                                                       \
    af[e] = f2bf(p);                                                 \
  }

  for (int j0 = jlo; j0 < jlo + JCHUNK; j0 += 32) {
    int jj = j0 + grp * 8;
    const int4* ap = (const int4*)(adjRow + jj);
    int4 A0 = ap[0];
    int4 A1 = ap[1];
    const uint4* pp = (const uint4*)(pE + jj);
    uint4 P0 = pp[0];
    uint4 P1 = pp[1];
    s16x8 af;
    PROC(A0.x, P0.x, 0); PROC(A0.y, P0.y, 1);
    PROC(A0.z, P0.z, 2); PROC(A0.w, P0.w, 3);
    PROC(A1.x, P1.x, 4); PROC(A1.y, P1.y, 5);
    PROC(A1.z, P1.z, 6); PROC(A1.w, P1.w, 7);
    const unsigned short* hTj = hT + jj;
#pragma unroll
    for (int n = 0; n < 8; n++) {
      s16x8 bf = *(const s16x8*)(hTj + (size_t)(n * 16 + lrow) * N_NODES);
      acc[n] = __builtin_amdgcn_mfma_f32_16x16x32_bf16(af, bf, acc[n], 0, 0, 0);
    }
  }
#undef PROC

  // row denominator: lanes l, l^16, l^32, l^48 share lrow (same row i)
  dsum += __shfl_xor(dsum, 16, 64);
  dsum += __shfl_xor(dsum, 32, 64);
  if (lane < 16) denws[js * N_NODES + waveRow + lane] = dsum;

#pragma unroll
  for (int n = 0; n < 8; n++)
#pragma unroll
    for (int r = 0; r < 4; r++)
      accws[((size_t)js * N_NODES + waveRow + grp * 4 + r) * F_OUT + n * 16 + lrow] =
          acc[n][r];
}

// ---------------- k3: combine partials, normalize, elu ----------------
template <int JS>
__global__ void k3_fin(const float* __restrict__ accws,
                       const float* __restrict__ denws, float* __restrict__ out) {
  int idx = blockIdx.x * 256 + threadIdx.x;   // 1048576 elements
  int i = idx >> 7;
  const int S = N_NODES * F_OUT;
  float s = 0.f, d = 0.f;
#pragma unroll
  for (int js = 0; js < JS; js++) {
    s += accws[idx + (size_t)js * S];
    d += denws[i + js * N_NODES];
  }
  float v = s / d;
  out[idx] = v > 0.f ? v : expm1f(v);
}

extern "C" void kernel_launch(void* const* d_in, const int* in_sizes, int n_in,
                              void* d_out, int out_size, void* d_ws, size_t ws_size,
                              hipStream_t stream) {
  const float* X   = (const float*)d_in[0];
  const int*   adj = (const int*)d_in[1];
  const float* W   = (const float*)d_in[2];
  const float* a   = (const float*)d_in[3];
  float* out = (float*)d_out;

  char* ws = (char*)d_ws;
  size_t off = 0;
  unsigned short* WT = (unsigned short*)(ws + off); off += (size_t)F_OUT * F_IN * 2;
  unsigned short* Xb = (unsigned short*)(ws + off); off += (size_t)N_NODES * F_IN * 2;
  unsigned short* hT = (unsigned short*)(ws + off); off += (size_t)F_OUT * N_NODES * 2;
  f32x4* rowdat = (f32x4*)(ws + off); off += (size_t)N_NODES * 16;
  unsigned* pE = (unsigned*)(ws + off); off += (size_t)N_NODES * 4;
  float* wa = (float*)(ws + off); off += (size_t)2 * F_IN * 4;
  float* accws = (float*)(ws + off);
  size_t base = off;
  (void)in_sizes; (void)n_in; (void)out_size;

  k0a_wt<<<(F_IN * F_OUT) / 256, 256, 0, stream>>>(W, WT);
  k0c_wa<<<2, 256, 0, stream>>>(W, a, wa);
  k0b_x<<<N_NODES / 4, 256, 0, stream>>>(X, wa, Xb, rowdat, pE);
  k1_gemm<<<(N_NODES / 64) * 2, 256, 0, stream>>>(WT, Xb, hT);

  // JS=16 needs base + 16*(4MB + 32KB); fall back to JS=4 if ws is small.
  size_t need16 = base + 16ull * ((size_t)N_NODES * F_OUT * 4 + N_NODES * 4);
  if (ws_size >= need16) {
    constexpr int JS = 16;
    float* denws = (float*)(ws + base + (size_t)JS * N_NODES * F_OUT * 4);
    k2_main<JS><<<(N_NODES / 64) * JS, 256, 0, stream>>>(adj, hT, rowdat, pE, accws, denws);
    k3_fin<JS><<<(N_NODES * F_OUT) / 256, 256, 0, stream>>>(accws, denws, out);
  } else {
    constexpr int JS = 4;
    float* denws = (float*)(ws + base + (size_t)JS * N_NODES * F_OUT * 4);
    k2_main<JS><<<(N_NODES / 64) * JS, 256, 0, stream>>>(adj, hT, rowdat, pE, accws, denws);
    k3_fin<JS><<<(N_NODES * F_OUT) / 256, 256, 0, stream>>>(accws, denws, out);
  }
}